// Round 4
// baseline (506.832 us; speedup 1.0000x reference)
//
#include <hip/hip_runtime.h>
#include <hip/hip_bf16.h>

// ScaledDotProductAttention: B=16, N=2048, D=64. q/k/v fp32, mask int32,
// out fp32. scores = q@k^T/sqrt(N); masked -> -1000; softmax over dim=1
// (COLUMN-wise over n); out = attn @ v.
// out[n,d] = sum_m exp(s[n,m])*[!mask] * (v[m,d]/colsum[m]).
//
// R16 = R15 with pass-2 de-serialized (R15 post-mortem: recompute arc
// regressed +32us purely from out2's structure, not its bytes):
//   1. pbuf DOUBLE-BUFFERED (pbA/pbB, explicit 2-step body, compile-time
//      buffer names): breaks the ds_write->ds_read->ds_write WAR chain
//      that serialized all 64 mi iterations at DS latency.
//   2. MSPLIT=2: m-contraction split across grid.z -> 1024 blocks,
//      4 waves/SIMD (was 2); f32 partials + tiny reduce (no atomics,
//      R13 lesson). +24 MB traffic (~4us) for 2x latency hiding.
// Bytes ~355 MB vs R12's 825 MB; target is R12's pv+score minus the
// 512 MB pstore round-trip (~-80us) with pass-2 compute ~= pv's BW cost.
// Pipeline: cvt -> cspack -> vprep -> out2(partials) -> reduce2.

#define B_ 16
#define N_ 2048
#define D_ 64
#define SCALE 0.022097086912079608f  // 1/sqrt(2048)
#define NCH 8                        // n-chunks for pass1 grid.z
#define MSPLIT 2                     // pass2 m-split

typedef __attribute__((ext_vector_type(8))) short bf16x8;
typedef __attribute__((ext_vector_type(4))) float f32x4;
typedef unsigned char u8;

static __device__ __forceinline__ short f2bf(float x) {
  unsigned u = __float_as_uint(x);
  return (short)((u + 0x7FFF + ((u >> 16) & 1)) >> 16);
}

static __device__ __forceinline__ bf16x8 load8(const short* p) {
  return *reinterpret_cast<const bf16x8*>(p);
}

static __device__ __forceinline__ bf16x8 load8f(const float* p) {
  const f32x4 a = *reinterpret_cast<const f32x4*>(p);
  const f32x4 b = *reinterpret_cast<const f32x4*>(p + 4);
  bf16x8 r;
  r[0] = f2bf(a[0]); r[1] = f2bf(a[1]); r[2] = f2bf(a[2]); r[3] = f2bf(a[3]);
  r[4] = f2bf(b[0]); r[5] = f2bf(b[1]); r[6] = f2bf(b[2]); r[7] = f2bf(b[3]);
  return r;
}

// ---------------- 1. fp32 -> bf16 convert (q: y=0, k: y=1) ----------------
__global__ __launch_bounds__(256) void cvt_bf16(const float* __restrict__ q,
                                                const float* __restrict__ k,
                                                short* __restrict__ qb,
                                                short* __restrict__ kb) {
  const size_t i = ((size_t)blockIdx.x * 256 + threadIdx.x) * 8;
  const float* src = blockIdx.y ? k : q;
  short* dst = blockIdx.y ? kb : qb;
  *reinterpret_cast<bf16x8*>(dst + i) = load8f(src + i);
}

// ------- 2. pass1: colsum partials + packed mask ------------------------
// grid (B, N/128, NCH); 4 waves/block; wave owns 32 m-cols (m0 = y*128 +
// wave*32), iterates its 256-row n-chunk in 16-row tiles (16 iters).
// pk[b][n16][mi][lane]: 1 byte/lane/tile, bit (cg*4+r) = mask of
// (n = n16*16 + lhi*4 + r, m = mi*32 + cg*16 + l15) — lane-symmetric with
// pass2's tile decomposition. csp[b][z][m]: colsum partial (registers).
__global__ __launch_bounds__(256) void cspack_kernel(
    const short* __restrict__ qb, const short* __restrict__ kb,
    const int* __restrict__ mask, u8* __restrict__ pk,
    float* __restrict__ csp) {
  const int b = blockIdx.x;
  const int wave = threadIdx.x >> 6;
  const int lane = threadIdx.x & 63;
  const int l15 = lane & 15;
  const int lhi = lane >> 4;
  const int m0 = blockIdx.y * 128 + wave * 32;
  const int mi = m0 >> 5;
  const int nbase = blockIdx.z * (N_ / NCH);  // 256-row chunk

  const short* qbb = qb + (size_t)b * N_ * D_;
  const short* kbb = kb + (size_t)b * N_ * D_;
  const int* maskb = mask + (size_t)b * N_ * N_;

  // K-fragments: loop-invariant (m fixed per wave) — loaded ONCE.
  bf16x8 kf[2][2];
#pragma unroll
  for (int cg = 0; cg < 2; ++cg) {
    kf[cg][0] = load8(kbb + (m0 + cg * 16 + l15) * D_ + lhi * 8);
    kf[cg][1] = load8(kbb + (m0 + cg * 16 + l15) * D_ + 32 + lhi * 8);
  }

  float cs0 = 0.f, cs1 = 0.f;  // register colsum partials

  for (int n0 = nbase; n0 < nbase + N_ / NCH; n0 += 16) {
    // independent mask words up-front (fill vmem queue); no fences below
    // so the scheduler can hoist next-iter loads freely.
    int mk[2][4];
#pragma unroll
    for (int cg = 0; cg < 2; ++cg)
#pragma unroll
      for (int r = 0; r < 4; ++r)
        mk[cg][r] =
            maskb[(size_t)(n0 + lhi * 4 + r) * N_ + m0 + cg * 16 + l15];
    // Q A-fragments for this n-tile
    const bf16x8 qf0 = load8(qbb + (n0 + l15) * D_ + lhi * 8);
    const bf16x8 qf1 = load8(qbb + (n0 + l15) * D_ + 32 + lhi * 8);
    unsigned pbyte = 0;
#pragma unroll
    for (int cg = 0; cg < 2; ++cg) {
      f32x4 acc = {0.f, 0.f, 0.f, 0.f};
      acc = __builtin_amdgcn_mfma_f32_16x16x32_bf16(qf0, kf[cg][0], acc, 0, 0, 0);
      acc = __builtin_amdgcn_mfma_f32_16x16x32_bf16(qf1, kf[cg][1], acc, 0, 0, 0);
      float cp = 0.f;
#pragma unroll
      for (int r = 0; r < 4; ++r) {
        // C-layout: row n = n0+lhi*4+r, col m = m0+cg*16+l15
        const float p = mk[cg][r] ? 0.f : __expf(acc[r] * SCALE);
        cp += p;
        pbyte |= (mk[cg][r] ? 1u : 0u) << (cg * 4 + r);
      }
      if (cg == 0) cs0 += cp; else cs1 += cp;
    }
    const int n16 = n0 >> 4;
    pk[(((size_t)b * 128 + n16) * 64 + mi) * 64 + lane] = (u8)pbyte;
  }

  // fold colsum across the 4 row-groups (lanes xor 16, 32), store once.
  cs0 += __shfl_xor(cs0, 16, 64);
  cs0 += __shfl_xor(cs0, 32, 64);
  cs1 += __shfl_xor(cs1, 16, 64);
  cs1 += __shfl_xor(cs1, 32, 64);
  float* cspz = csp + ((size_t)b * NCH + blockIdx.z) * N_;
  if (lane < 16) {
    cspz[m0 + l15] = cs0;
    cspz[m0 + 16 + l15] = cs1;
  }
}

// ------- 3. vt[b][d][m] = bf16(v[b][m][d] / sum_z csp[b][z][m]) -----
// grid (B, N/64); 64 m-columns per block; folds the 8 partials.
__global__ __launch_bounds__(256) void vprep_kernel(
    const float* __restrict__ v, const float* __restrict__ csp,
    short* __restrict__ vt) {
  const int b = blockIdx.x;
  const int m0 = blockIdx.y * 64;
  const int tid = threadIdx.x;
  __shared__ float csl[4][64];
  __shared__ float cst[64];
  __shared__ float lds[64][65];

  {
    const int col = m0 + (tid & 63);
    const int q4 = tid >> 6;
    float s = 0.f;
#pragma unroll
    for (int j = 0; j < 2; ++j)
      s += csp[((size_t)b * NCH + q4 * 2 + j) * N_ + col];
    csl[q4][tid & 63] = s;
  }
  __syncthreads();
  if (tid < 64) cst[tid] = csl[0][tid] + csl[1][tid] + csl[2][tid] + csl[3][tid];
  __syncthreads();

  const float* vb = v + (size_t)b * N_ * D_;
#pragma unroll
  for (int pass = 0; pass < 4; ++pass) {
    const int mloc = pass * 16 + (tid >> 4);
    const int d4 = (tid & 15) * 4;
    const f32x4 x = *reinterpret_cast<const f32x4*>(vb + (m0 + mloc) * D_ + d4);
    const float ic = 1.0f / cst[mloc];
    lds[mloc][d4 + 0] = x[0] * ic;
    lds[mloc][d4 + 1] = x[1] * ic;
    lds[mloc][d4 + 2] = x[2] * ic;
    lds[mloc][d4 + 3] = x[3] * ic;
  }
  __syncthreads();
  const int d = tid >> 2;
  const int seg = tid & 3;
  bf16x8 o0, o1;
#pragma unroll
  for (int i = 0; i < 8; ++i) o0[i] = f2bf(lds[seg * 16 + i][d]);
#pragma unroll
  for (int i = 0; i < 8; ++i) o1[i] = f2bf(lds[seg * 16 + 8 + i][d]);
  short* dst = vt + (size_t)b * D_ * N_ + (size_t)d * N_ + m0 + seg * 16;
  *reinterpret_cast<bf16x8*>(dst) = o0;
  *reinterpret_cast<bf16x8*>(dst + 8) = o1;
}

// ------- 4. pass2: outp[z] = P @ vt over mi in [z*32, z*32+32) ---------
// grid (B, N/64, MSPLIT); 4 waves; wave owns 16 n-rows, 32 mi steps.
// Double-buffered pbuf (pbA/pbB alternate per step, compile-time names):
// step i's ds_read overlaps step i+1's kf loads / MFMA / ds_write.
// HBM streams: pk 8 MB + partial out 16W; kb/vt/qb L2-resident.
#define OSTEP(MI, PB)                                                          \
  {                                                                            \
    const int m0s = (miBase + (MI)) * 32;                                      \
    const unsigned pbyte = pks[wave][(MI) * 64 + lane];                        \
    _Pragma("unroll") for (int cg = 0; cg < 2; ++cg) {                         \
      const bf16x8 kf0 = load8(kbb + (m0s + cg * 16 + l15) * D_ + lhi * 8);    \
      const bf16x8 kf1 =                                                       \
          load8(kbb + (m0s + cg * 16 + l15) * D_ + 32 + lhi * 8);              \
      f32x4 acc = {0.f, 0.f, 0.f, 0.f};                                        \
      acc = __builtin_amdgcn_mfma_f32_16x16x32_bf16(qf0, kf0, acc, 0, 0, 0);   \
      acc = __builtin_amdgcn_mfma_f32_16x16x32_bf16(qf1, kf1, acc, 0, 0, 0);   \
      _Pragma("unroll") for (int r = 0; r < 4; ++r) {                          \
        const float p =                                                        \
            ((pbyte >> (cg * 4 + r)) & 1u) ? 0.f : __expf(acc[r] * SCALE);     \
        PB[wave][lhi * 4 + r][cg * 16 + l15] = f2bf(p);                        \
      }                                                                        \
    }                                                                          \
    const bf16x8 pa =                                                          \
        *reinterpret_cast<const bf16x8*>(&PB[wave][l15][lhi * 8]);             \
    _Pragma("unroll") for (int dsub = 0; dsub < 4; ++dsub) {                   \
      const bf16x8 vf =                                                        \
          load8(vtb + (size_t)(dsub * 16 + l15) * N_ + m0s + lhi * 8);         \
      oacc[dsub] =                                                             \
          __builtin_amdgcn_mfma_f32_16x16x32_bf16(pa, vf, oacc[dsub], 0, 0, 0);\
    }                                                                          \
  }

__global__ __launch_bounds__(256) void out2_kernel(
    const short* __restrict__ qb, const short* __restrict__ kb,
    const u8* __restrict__ pk, const short* __restrict__ vt,
    float* __restrict__ outp) {
  const int b = blockIdx.x;
  const int wave = threadIdx.x >> 6;
  const int lane = threadIdx.x & 63;
  const int l15 = lane & 15;
  const int lhi = lane >> 4;
  const int n16 = blockIdx.y * 4 + wave;
  const int n0 = n16 * 16;
  const int miBase = blockIdx.z * (64 / MSPLIT);

  const short* qbb = qb + (size_t)b * N_ * D_;
  const short* kbb = kb + (size_t)b * N_ * D_;
  const short* vtb = vt + (size_t)b * D_ * N_;

  // Q A-fragments: loop-invariant (n fixed per wave).
  const bf16x8 qf0 = load8(qbb + (n0 + l15) * D_ + lhi * 8);
  const bf16x8 qf1 = load8(qbb + (n0 + l15) * D_ + 32 + lhi * 8);

  // Stage this wave's pk slab (32 mi x 64 lanes = 2 KB) into LDS: one
  // bulk coalesced load, then per-step ds_read_u8. Wave-private.
  __shared__ __align__(16) u8 pks[4][2048];
  __shared__ __align__(16) short pbA[4][16][40];  // stride 80B: 2-way-free
  __shared__ __align__(16) short pbB[4][16][40];
  {
    const f32x4* src = reinterpret_cast<const f32x4*>(
        pk + (((size_t)b * 128 + n16) * 64 + miBase) * 64);
    f32x4* dst = reinterpret_cast<f32x4*>(pks[wave]);
#pragma unroll
    for (int j = 0; j < 2; ++j) dst[j * 64 + lane] = src[j * 64 + lane];
  }

  f32x4 oacc[4];
#pragma unroll
  for (int d = 0; d < 4; ++d) oacc[d] = (f32x4){0.f, 0.f, 0.f, 0.f};

  for (int mi2 = 0; mi2 < 64 / MSPLIT; mi2 += 2) {
    OSTEP(mi2, pbA);
    OSTEP(mi2 + 1, pbB);
  }

  float* dst = outp + ((size_t)blockIdx.z * B_ + b) * N_ * D_;
#pragma unroll
  for (int dsub = 0; dsub < 4; ++dsub)
#pragma unroll
    for (int r = 0; r < 4; ++r)
      dst[(size_t)(n0 + lhi * 4 + r) * D_ + dsub * 16 + l15] = oacc[dsub][r];
}

// ------- 5. reduce2: out = outp[0] + outp[1] (vectorized) -------
__global__ __launch_bounds__(256) void reduce2_kernel(
    const float* __restrict__ outp, float* __restrict__ out) {
  const size_t i = ((size_t)blockIdx.x * 256 + threadIdx.x) * 4;
  const f32x4 a = *reinterpret_cast<const f32x4*>(outp + i);
  const f32x4 c =
      *reinterpret_cast<const f32x4*>(outp + (size_t)B_ * N_ * D_ + i);
  f32x4 r;
  r[0] = a[0] + c[0]; r[1] = a[1] + c[1];
  r[2] = a[2] + c[2]; r[3] = a[3] + c[3];
  *reinterpret_cast<f32x4*>(out + i) = r;
}

// ================= R2 fallback (small-workspace path), verified ============
__global__ __launch_bounds__(256) void colsum_fb(
    const float* __restrict__ q, const float* __restrict__ k,
    const int* __restrict__ mask, float* __restrict__ colsum) {
  const int b = blockIdx.x;
  const int wave = threadIdx.x >> 6;
  const int lane = threadIdx.x & 63;
  const int l15 = lane & 15;
  const int lhi = lane >> 4;
  const int m0 = blockIdx.y * 64 + wave * 16;
  const float* qbp = q + (size_t)b * N_ * D_;
  const float* kbp = k + (size_t)b * N_ * D_;
  const int* maskb = mask + (size_t)b * N_ * N_;
  const bf16x8 kf0 = load8f(kbp + (m0 + l15) * D_ + lhi * 8);
  const bf16x8 kf1 = load8f(kbp + (m0 + l15) * D_ + 32 + lhi * 8);
  float partial = 0.f;
  for (int n0 = 0; n0 < N_; n0 += 16) {
    bf16x8 qf0 = load8f(qbp + (n0 + l15) * D_ + lhi * 8);
    bf16x8 qf1 = load8f(qbp + (n0 + l15) * D_ + 32 + lhi * 8);
    f32x4 acc = {0.f, 0.f, 0.f, 0.f};
    acc = __builtin_amdgcn_mfma_f32_16x16x32_bf16(qf0, kf0, acc, 0, 0, 0);
    acc = __builtin_amdgcn_mfma_f32_16x16x32_bf16(qf1, kf1, acc, 0, 0, 0);
#pragma unroll
    for (int r = 0; r < 4; ++r) {
      const int n = n0 + lhi * 4 + r;
      partial +=
          maskb[(size_t)n * N_ + m0 + l15] ? 0.f : __expf(acc[r] * SCALE);
    }
  }
  partial += __shfl_xor(partial, 16, 64);
  partial += __shfl_xor(partial, 32, 64);
  if (lane < 16) colsum[(size_t)b * N_ + m0 + l15] = partial;
}

__global__ __launch_bounds__(256) void attn_out_fb(
    const float* __restrict__ q, const float* __restrict__ k,
    const float* __restrict__ v, const int* __restrict__ mask,
    const float* __restrict__ colsum, float* __restrict__ out) {
  const int b = blockIdx.x;
  const int wave = threadIdx.x >> 6;
  const int lane = threadIdx.x & 63;
  const int l15 = lane & 15;
  const int lhi = lane >> 4;
  const int n0 = blockIdx.y * 64 + wave * 16;
  const float* qbp = q + (size_t)b * N_ * D_;
  const float* kbp = k + (size_t)b * N_ * D_;
  const float* vbp = v + (size_t)b * N_ * D_;
  const int* maskb = mask + (size_t)b * N_ * N_;
  const float* csb = colsum + (size_t)b * N_;
  const bf16x8 qf0 = load8f(qbp + (n0 + l15) * D_ + lhi * 8);
  const bf16x8 qf1 = load8f(qbp + (n0 + l15) * D_ + 32 + lhi * 8);
  __shared__ __align__(16) short pbuf[4][16][32];
  f32x4 oacc[4];
#pragma unroll
  for (int d = 0; d < 4; ++d) oacc[d] = (f32x4){0.f, 0.f, 0.f, 0.f};
  for (int m0 = 0; m0 < N_; m0 += 32) {
#pragma unroll
    for (int cg = 0; cg < 2; ++cg) {
      const int mc = m0 + cg * 16;
      bf16x8 kf0 = load8f(kbp + (mc + l15) * D_ + lhi * 8);
      bf16x8 kf1 = load8f(kbp + (mc + l15) * D_ + 32 + lhi * 8);
      f32x4 acc = {0.f, 0.f, 0.f, 0.f};
      acc = __builtin_amdgcn_mfma_f32_16x16x32_bf16(qf0, kf0, acc, 0, 0, 0);
      acc = __builtin_amdgcn_mfma_f32_16x16x32_bf16(qf1, kf1, acc, 0, 0, 0);
      const float ic = 1.0f / csb[mc + l15];
#pragma unroll
      for (int r = 0; r < 4; ++r) {
        const int n = n0 + lhi * 4 + r;
        const float p = maskb[(size_t)n * N_ + mc + l15]
                            ? 0.f
                            : __expf(acc[r] * SCALE) * ic;
        pbuf[wave][lhi * 4 + r][cg * 16 + l15] = f2bf(p);
      }
    }
    __syncthreads();
    const bf16x8 pa =
        *reinterpret_cast<const bf16x8*>(&pbuf[wave][l15][lhi * 8]);
#pragma unroll
    for (int dsub = 0; dsub < 4; ++dsub) {
      bf16x8 vf;
#pragma unroll
      for (int j = 0; j < 8; ++j)
        vf[j] = f2bf(vbp[(m0 + lhi * 8 + j) * D_ + dsub * 16 + l15]);
      oacc[dsub] =
          __builtin_amdgcn_mfma_f32_16x16x32_bf16(pa, vf, oacc[dsub], 0, 0, 0);
    }
    __syncthreads();
  }
#pragma unroll
  for (int dsub = 0; dsub < 4; ++dsub)
#pragma unroll
    for (int r = 0; r < 4; ++r)
      out[(size_t)b * N_ * D_ + (size_t)(n0 + lhi * 4 + r) * D_ + dsub * 16 +
          l15] = oacc[dsub][r];
}

extern "C" void kernel_launch(void* const* d_in, const int* in_sizes, int n_in,
                              void* d_out, int out_size, void* d_ws,
                              size_t ws_size, hipStream_t stream) {
  const float* q = (const float*)d_in[0];
  const float* k = (const float*)d_in[1];
  const float* v = (const float*)d_in[2];
  const int* mask = (const int*)d_in[3];
  float* out = (float*)d_out;

  // workspace layout (~37 MB total)
  const size_t MB = 1024 * 1024;
  const size_t qb_off = 0;                // 4 MB qbf
  const size_t kb_off = qb_off + 4 * MB;  // 4 MB kbf
  const size_t vt_off = kb_off + 4 * MB;  // 4 MB vt
  const size_t cs_off = vt_off + 4 * MB;  // 1 MB csp (8 partials)
  const size_t pk_off = cs_off + 1 * MB;  // 8 MB packed mask
  const size_t op_off = pk_off + 8 * MB;  // 16 MB out partials (2x)
  const size_t need = op_off + 16 * MB;

  if (ws_size >= need) {
    short* qbf = (short*)((char*)d_ws + qb_off);
    short* kbf = (short*)((char*)d_ws + kb_off);
    short* vt = (short*)((char*)d_ws + vt_off);
    float* csp = (float*)((char*)d_ws + cs_off);
    u8* pk = (u8*)((char*)d_ws + pk_off);
    float* outp = (float*)((char*)d_ws + op_off);

    cvt_bf16<<<dim3((B_ * N_ * D_) / (256 * 8), 2), 256, 0, stream>>>(
        q, k, qbf, kbf);
    cspack_kernel<<<dim3(B_, N_ / 128, NCH), 256, 0, stream>>>(qbf, kbf, mask,
                                                               pk, csp);
    vprep_kernel<<<dim3(B_, N_ / 64), 256, 0, stream>>>(v, csp, vt);
    out2_kernel<<<dim3(B_, N_ / 64, MSPLIT), 256, 0, stream>>>(qbf, kbf, pk,
                                                               vt, outp);
    reduce2_kernel<<<dim3((B_ * N_ * D_) / (256 * 4)), 256, 0, stream>>>(outp,
                                                                         out);
  } else {
    float* colsum = (float*)d_ws;  // 128 KB
    colsum_fb<<<dim3(B_, N_ / 64), 256, 0, stream>>>(q, k, mask, colsum);
    attn_out_fb<<<dim3(B_, N_ / 64), 256, 0, stream>>>(q, k, v, mask, colsum,
                                                       out);
  }
}

// Round 5
// 451.571 us; speedup vs baseline: 1.1224x; 1.1224x over previous
//
#include <hip/hip_runtime.h>
#include <hip/hip_bf16.h>

// ScaledDotProductAttention: B=16, N=2048, D=64. q/k/v fp32, mask int32,
// out fp32. scores = q@k^T/sqrt(N); masked -> -1000; softmax over dim=1
// (COLUMN-wise over n); out = attn @ v.
// out[n,d] = sum_m exp(s[n,m])*[!mask] * (v[m,d]/colsum[m]).
//
// R17 = R12 (best measured: 461.3/462.4; R13-R16 all regressed) + one
// cache-residency change:
//   NON-TEMPORAL loads on every read-exactly-once stream (mask in score,
//   q/k fp32 in cvt, v in vprep). The 268 MB mask stream was flushing
//   the 256 MB L3 between score's pstore WRITE (128 MB) and pv's pstore
//   READ. With mask NT, L3 holds pstore+qb/kb/vt (~140 MB) -> pv's
//   256 MB of pstore reads become L3 hits instead of HBM fetches.
// Pipeline (4 dispatches): cvt -> score -> vprep -> pv(direct out).

#define B_ 16
#define N_ 2048
#define D_ 64
#define SCALE 0.022097086912079608f  // 1/sqrt(2048)
#define NCH 8                        // n-chunks for score grid.z

typedef __attribute__((ext_vector_type(8))) short bf16x8;
typedef __attribute__((ext_vector_type(4))) float f32x4;

static __device__ __forceinline__ short f2bf(float x) {
  unsigned u = __float_as_uint(x);
  return (short)((u + 0x7FFF + ((u >> 16) & 1)) >> 16);
}

static __device__ __forceinline__ bf16x8 load8(const short* p) {
  return *reinterpret_cast<const bf16x8*>(p);
}

static __device__ __forceinline__ bf16x8 load8f(const float* p) {
  const f32x4 a = *reinterpret_cast<const f32x4*>(p);
  const f32x4 b = *reinterpret_cast<const f32x4*>(p + 4);
  bf16x8 r;
  r[0] = f2bf(a[0]); r[1] = f2bf(a[1]); r[2] = f2bf(a[2]); r[3] = f2bf(a[3]);
  r[4] = f2bf(b[0]); r[5] = f2bf(b[1]); r[6] = f2bf(b[2]); r[7] = f2bf(b[3]);
  return r;
}

// non-temporal variant: read-once fp32 streams (q/k in cvt) — nt flag
// keeps them from evicting L3-resident intermediates.
static __device__ __forceinline__ bf16x8 load8f_nt(const float* p) {
  const f32x4 a = __builtin_nontemporal_load(reinterpret_cast<const f32x4*>(p));
  const f32x4 b =
      __builtin_nontemporal_load(reinterpret_cast<const f32x4*>(p + 4));
  bf16x8 r;
  r[0] = f2bf(a[0]); r[1] = f2bf(a[1]); r[2] = f2bf(a[2]); r[3] = f2bf(a[3]);
  r[4] = f2bf(b[0]); r[5] = f2bf(b[1]); r[6] = f2bf(b[2]); r[7] = f2bf(b[3]);
  return r;
}

// ---------------- 1. fp32 -> bf16 convert (q: y=0, k: y=1) ----------------
__global__ __launch_bounds__(256) void cvt_bf16(const float* __restrict__ q,
                                                const float* __restrict__ k,
                                                short* __restrict__ qb,
                                                short* __restrict__ kb) {
  const size_t i = ((size_t)blockIdx.x * 256 + threadIdx.x) * 8;
  const float* src = blockIdx.y ? k : q;
  short* dst = blockIdx.y ? kb : qb;
  *reinterpret_cast<bf16x8*>(dst + i) = load8f_nt(src + i);
}

// ------- 2. score (m-major): P = exp(S)*!mask, A-frag-ready + csp -------
// grid (B, N/128, NCH); 4 waves/block; wave owns 32 m-cols (m0 = y*128 +
// wave*32), iterates its 256-row n-chunk in 16-row tiles (16 iters).
// pstore: [b][n16][mi][lane][8] shorts (n16 = n/16, mi = m/32) — lane's PV
// A-fragment is one contiguous 16B chunk; block writes 4KB contig per iter.
// csp[b][z][m]: colsum partial over chunk z's 256 rows (register-held).
// Mask loads NON-TEMPORAL: 268 MB read-once stream must not flush the
// L3-resident pstore between score's write and pv's read.
__global__ __launch_bounds__(256) void score_kernel(
    const short* __restrict__ qb, const short* __restrict__ kb,
    const int* __restrict__ mask, short* __restrict__ pstore,
    float* __restrict__ csp) {
  const int b = blockIdx.x;
  const int wave = threadIdx.x >> 6;
  const int lane = threadIdx.x & 63;
  const int l15 = lane & 15;
  const int lhi = lane >> 4;
  const int m0 = blockIdx.y * 128 + wave * 32;
  const int mi = m0 >> 5;
  const int nbase = blockIdx.z * (N_ / NCH);  // 256-row chunk

  const short* qbb = qb + (size_t)b * N_ * D_;
  const short* kbb = kb + (size_t)b * N_ * D_;
  const int* maskb = mask + (size_t)b * N_ * N_;

  // K-fragments: loop-invariant (m fixed per wave) — loaded ONCE.
  bf16x8 kf[2][2];
#pragma unroll
  for (int cg = 0; cg < 2; ++cg) {
    kf[cg][0] = load8(kbb + (m0 + cg * 16 + l15) * D_ + lhi * 8);
    kf[cg][1] = load8(kbb + (m0 + cg * 16 + l15) * D_ + 32 + lhi * 8);
  }

  __shared__ __align__(16) short pbuf[4][16][40];  // stride 80B: 2-way-free

  float cs0 = 0.f, cs1 = 0.f;  // register colsum partials (cols m0+cg*16+l15)

  for (int n0 = nbase; n0 < nbase + N_ / NCH; n0 += 16) {
    // independent mask words up-front (fill vmem queue); NT: stream, don't
    // allocate in L3.
    int mk[2][4];
#pragma unroll
    for (int cg = 0; cg < 2; ++cg)
#pragma unroll
      for (int r = 0; r < 4; ++r)
        mk[cg][r] = __builtin_nontemporal_load(
            &maskb[(size_t)(n0 + lhi * 4 + r) * N_ + m0 + cg * 16 + l15]);
    // Q A-fragments for this n-tile
    const bf16x8 qf0 = load8(qbb + (n0 + l15) * D_ + lhi * 8);
    const bf16x8 qf1 = load8(qbb + (n0 + l15) * D_ + 32 + lhi * 8);
#pragma unroll
    for (int cg = 0; cg < 2; ++cg) {
      f32x4 acc = {0.f, 0.f, 0.f, 0.f};
      acc = __builtin_amdgcn_mfma_f32_16x16x32_bf16(qf0, kf[cg][0], acc, 0, 0, 0);
      acc = __builtin_amdgcn_mfma_f32_16x16x32_bf16(qf1, kf[cg][1], acc, 0, 0, 0);
      float cp = 0.f;
#pragma unroll
      for (int r = 0; r < 4; ++r) {
        // C-layout: row n = n0+lhi*4+r, col m = m0+cg*16+l15
        const float p = mk[cg][r] ? 0.f : __expf(acc[r] * SCALE);
        cp += p;
        pbuf[wave][lhi * 4 + r][cg * 16 + l15] = f2bf(p);
      }
      if (cg == 0) cs0 += cp; else cs1 += cp;
    }
    // pbuf is wave-private: DS in-order within a wave; compiler fence only.
    __builtin_amdgcn_wave_barrier();
    // PV A-fragment unit (16n x 32m): A[n=l15][k=lhi*8+j], one b128.
    const bf16x8 pa =
        *reinterpret_cast<const bf16x8*>(&pbuf[wave][l15][lhi * 8]);
    const int n16 = n0 >> 4;
    *reinterpret_cast<bf16x8*>(
        pstore + (((size_t)b * 128 + n16) * 64 + mi) * 512 + lane * 8) = pa;
    __builtin_amdgcn_wave_barrier();  // keep next iter's writes after read
  }

  // fold colsum across the 4 row-groups (lanes xor 16, 32), store once.
  cs0 += __shfl_xor(cs0, 16, 64);
  cs0 += __shfl_xor(cs0, 32, 64);
  cs1 += __shfl_xor(cs1, 16, 64);
  cs1 += __shfl_xor(cs1, 32, 64);
  float* cspz = csp + ((size_t)b * NCH + blockIdx.z) * N_;
  if (lane < 16) {
    cspz[m0 + l15] = cs0;
    cspz[m0 + 16 + l15] = cs1;
  }
}

// ------- 3. vt[b][d][m] = bf16(v[b][m][d] / sum_z csp[b][z][m]) -----
// grid (B, N/64); 64 m-columns per block; folds the 8 partials.
__global__ __launch_bounds__(256) void vprep_kernel(
    const float* __restrict__ v, const float* __restrict__ csp,
    short* __restrict__ vt) {
  const int b = blockIdx.x;
  const int m0 = blockIdx.y * 64;
  const int tid = threadIdx.x;
  __shared__ float csl[4][64];
  __shared__ float cst[64];
  __shared__ float lds[64][65];

  // fold 8 partials: quarter q4 = tid>>6 sums 2 of them for col tid&63
  {
    const int col = m0 + (tid & 63);
    const int q4 = tid >> 6;
    float s = 0.f;
#pragma unroll
    for (int j = 0; j < 2; ++j)
      s += csp[((size_t)b * NCH + q4 * 2 + j) * N_ + col];
    csl[q4][tid & 63] = s;
  }
  __syncthreads();
  if (tid < 64) cst[tid] = csl[0][tid] + csl[1][tid] + csl[2][tid] + csl[3][tid];
  __syncthreads();

  const float* vb = v + (size_t)b * N_ * D_;
#pragma unroll
  for (int pass = 0; pass < 4; ++pass) {
    const int mloc = pass * 16 + (tid >> 4);
    const int d4 = (tid & 15) * 4;
    const f32x4 x = __builtin_nontemporal_load(
        reinterpret_cast<const f32x4*>(vb + (m0 + mloc) * D_ + d4));
    const float ic = 1.0f / cst[mloc];
    lds[mloc][d4 + 0] = x[0] * ic;
    lds[mloc][d4 + 1] = x[1] * ic;
    lds[mloc][d4 + 2] = x[2] * ic;
    lds[mloc][d4 + 3] = x[3] * ic;
  }
  __syncthreads();
  const int d = tid >> 2;
  const int seg = tid & 3;
  bf16x8 o0, o1;
#pragma unroll
  for (int i = 0; i < 8; ++i) o0[i] = f2bf(lds[seg * 16 + i][d]);
#pragma unroll
  for (int i = 0; i < 8; ++i) o1[i] = f2bf(lds[seg * 16 + 8 + i][d]);
  short* dst = vt + (size_t)b * D_ * N_ + (size_t)d * N_ + m0 + seg * 16;
  *reinterpret_cast<bf16x8*>(dst) = o0;
  *reinterpret_cast<bf16x8*>(dst + 8) = o1;
}

// ------- 4. pv: out = P @ vt (full m-range, direct output) -------
// grid (B, N/64); pure streaming GEMM: 1 A-frag + 4 B-frag loads + 4 MFMA
// per iter; no LDS, no barriers, no partials. pstore reads should now be
// L3 hits (mask stream NT'd in score).
__global__ __launch_bounds__(256) void pv_kernel(const short* __restrict__ pstore,
                                                 const short* __restrict__ vt,
                                                 float* __restrict__ out) {
  const int b = blockIdx.x;
  const int wave = threadIdx.x >> 6;
  const int lane = threadIdx.x & 63;
  const int l15 = lane & 15;
  const int lhi = lane >> 4;
  const int n0 = blockIdx.y * 64 + wave * 16;
  const int n16 = blockIdx.y * 4 + wave;

  const short* psb =
      pstore + (((size_t)b * 128 + n16) * 64) * 512 + (size_t)lane * 8;
  const short* vtb = vt + (size_t)b * D_ * N_;

  f32x4 oacc[4];
#pragma unroll
  for (int d = 0; d < 4; ++d) oacc[d] = (f32x4){0.f, 0.f, 0.f, 0.f};

#pragma unroll 2
  for (int mi = 0; mi < 64; ++mi) {
    const bf16x8 pa = load8(psb + (size_t)mi * 512);
    const int m0 = mi * 32;
#pragma unroll
    for (int dsub = 0; dsub < 4; ++dsub) {
      const bf16x8 vf =
          load8(vtb + (size_t)(dsub * 16 + l15) * N_ + m0 + lhi * 8);
      oacc[dsub] =
          __builtin_amdgcn_mfma_f32_16x16x32_bf16(pa, vf, oacc[dsub], 0, 0, 0);
    }
  }

  float* dst = out + (size_t)b * N_ * D_;
#pragma unroll
  for (int dsub = 0; dsub < 4; ++dsub)
#pragma unroll
    for (int r = 0; r < 4; ++r)
      dst[(size_t)(n0 + lhi * 4 + r) * D_ + dsub * 16 + l15] = oacc[dsub][r];
}

// ================= R2 fallback (small-workspace path), verified ============
__global__ __launch_bounds__(256) void colsum_fb(
    const float* __restrict__ q, const float* __restrict__ k,
    const int* __restrict__ mask, float* __restrict__ colsum) {
  const int b = blockIdx.x;
  const int wave = threadIdx.x >> 6;
  const int lane = threadIdx.x & 63;
  const int l15 = lane & 15;
  const int lhi = lane >> 4;
  const int m0 = blockIdx.y * 64 + wave * 16;
  const float* qbp = q + (size_t)b * N_ * D_;
  const float* kbp = k + (size_t)b * N_ * D_;
  const int* maskb = mask + (size_t)b * N_ * N_;
  const bf16x8 kf0 = load8f(kbp + (m0 + l15) * D_ + lhi * 8);
  const bf16x8 kf1 = load8f(kbp + (m0 + l15) * D_ + 32 + lhi * 8);
  float partial = 0.f;
  for (int n0 = 0; n0 < N_; n0 += 16) {
    bf16x8 qf0 = load8f(qbp + (n0 + l15) * D_ + lhi * 8);
    bf16x8 qf1 = load8f(qbp + (n0 + l15) * D_ + 32 + lhi * 8);
    f32x4 acc = {0.f, 0.f, 0.f, 0.f};
    acc = __builtin_amdgcn_mfma_f32_16x16x32_bf16(qf0, kf0, acc, 0, 0, 0);
    acc = __builtin_amdgcn_mfma_f32_16x16x32_bf16(qf1, kf1, acc, 0, 0, 0);
#pragma unroll
    for (int r = 0; r < 4; ++r) {
      const int n = n0 + lhi * 4 + r;
      partial +=
          maskb[(size_t)n * N_ + m0 + l15] ? 0.f : __expf(acc[r] * SCALE);
    }
  }
  partial += __shfl_xor(partial, 16, 64);
  partial += __shfl_xor(partial, 32, 64);
  if (lane < 16) colsum[(size_t)b * N_ + m0 + l15] = partial;
}

__global__ __launch_bounds__(256) void attn_out_fb(
    const float* __restrict__ q, const float* __restrict__ k,
    const float* __restrict__ v, const int* __restrict__ mask,
    const float* __restrict__ colsum, float* __restrict__ out) {
  const int b = blockIdx.x;
  const int wave = threadIdx.x >> 6;
  const int lane = threadIdx.x & 63;
  const int l15 = lane & 15;
  const int lhi = lane >> 4;
  const int n0 = blockIdx.y * 64 + wave * 16;
  const float* qbp = q + (size_t)b * N_ * D_;
  const float* kbp = k + (size_t)b * N_ * D_;
  const float* vbp = v + (size_t)b * N_ * D_;
  const int* maskb = mask + (size_t)b * N_ * N_;
  const float* csb = colsum + (size_t)b * N_;
  const bf16x8 qf0 = load8f(qbp + (n0 + l15) * D_ + lhi * 8);
  const bf16x8 qf1 = load8f(qbp + (n0 + l15) * D_ + 32 + lhi * 8);
  __shared__ __align__(16) short pbuf[4][16][32];
  f32x4 oacc[4];
#pragma unroll
  for (int d = 0; d < 4; ++d) oacc[d] = (f32x4){0.f, 0.f, 0.f, 0.f};
  for (int m0 = 0; m0 < N_; m0 += 32) {
#pragma unroll
    for (int cg = 0; cg < 2; ++cg) {
      const int mc = m0 + cg * 16;
      bf16x8 kf0 = load8f(kbp + (mc + l15) * D_ + lhi * 8);
      bf16x8 kf1 = load8f(kbp + (mc + l15) * D_ + 32 + lhi * 8);
      f32x4 acc = {0.f, 0.f, 0.f, 0.f};
      acc = __builtin_amdgcn_mfma_f32_16x16x32_bf16(qf0, kf0, acc, 0, 0, 0);
      acc = __builtin_amdgcn_mfma_f32_16x16x32_bf16(qf1, kf1, acc, 0, 0, 0);
      const float ic = 1.0f / csb[mc + l15];
#pragma unroll
      for (int r = 0; r < 4; ++r) {
        const int n = n0 + lhi * 4 + r;
        const float p = maskb[(size_t)n * N_ + mc + l15]
                            ? 0.f
                            : __expf(acc[r] * SCALE) * ic;
        pbuf[wave][lhi * 4 + r][cg * 16 + l15] = f2bf(p);
      }
    }
    __syncthreads();
    const bf16x8 pa =
        *reinterpret_cast<const bf16x8*>(&pbuf[wave][l15][lhi * 8]);
#pragma unroll
    for (int dsub = 0; dsub < 4; ++dsub) {
      bf16x8 vf;
#pragma unroll
      for (int j = 0; j < 8; ++j)
        vf[j] = f2bf(vbp[(m0 + lhi * 8 + j) * D_ + dsub * 16 + l15]);
      oacc[dsub] =
          __builtin_amdgcn_mfma_f32_16x16x32_bf16(pa, vf, oacc[dsub], 0, 0, 0);
    }
    __syncthreads();
  }
#pragma unroll
  for (int dsub = 0; dsub < 4; ++dsub)
#pragma unroll
    for (int r = 0; r < 4; ++r)
      out[(size_t)b * N_ * D_ + (size_t)(n0 + lhi * 4 + r) * D_ + dsub * 16 +
          l15] = oacc[dsub][r];
}

extern "C" void kernel_launch(void* const* d_in, const int* in_sizes, int n_in,
                              void* d_out, int out_size, void* d_ws,
                              size_t ws_size, hipStream_t stream) {
  const float* q = (const float*)d_in[0];
  const float* k = (const float*)d_in[1];
  const float* v = (const float*)d_in[2];
  const int* mask = (const int*)d_in[3];
  float* out = (float*)d_out;

  // workspace layout (~141 MB total)
  const size_t MB = 1024 * 1024;
  const size_t qb_off = 0;                // 4 MB qbf
  const size_t kb_off = qb_off + 4 * MB;  // 4 MB kbf
  const size_t vt_off = kb_off + 4 * MB;  // 4 MB vt
  const size_t cs_off = vt_off + 4 * MB;  // 1 MB csp (8 partials)
  const size_t ps_off = cs_off + 1 * MB;  // 128 MB pstore
  const size_t need = ps_off + 128 * MB;

  if (ws_size >= need) {
    short* qbf = (short*)((char*)d_ws + qb_off);
    short* kbf = (short*)((char*)d_ws + kb_off);
    short* vt = (short*)((char*)d_ws + vt_off);
    float* csp = (float*)((char*)d_ws + cs_off);
    short* pstore = (short*)((char*)d_ws + ps_off);

    cvt_bf16<<<dim3((B_ * N_ * D_) / (256 * 8), 2), 256, 0, stream>>>(
        q, k, qbf, kbf);
    score_kernel<<<dim3(B_, N_ / 128, NCH), 256, 0, stream>>>(qbf, kbf, mask,
                                                              pstore, csp);
    vprep_kernel<<<dim3(B_, N_ / 64), 256, 0, stream>>>(v, csp, vt);
    pv_kernel<<<dim3(B_, N_ / 64), 256, 0, stream>>>(pstore, vt, out);
  } else {
    float* colsum = (float*)d_ws;  // 128 KB
    colsum_fb<<<dim3(B_, N_ / 64), 256, 0, stream>>>(q, k, mask, colsum);
    attn_out_fb<<<dim3(B_, N_ / 64), 256, 0, stream>>>(q, k, v, mask, colsum,
                                                       out);
  }
}